// Round 6
// baseline (236.227 us; speedup 1.0000x reference)
//
#include <hip/hip_runtime.h>
#include <cstdint>
#include <cstddef>

#define N_TOT 16384
#define DIM 512
#define EPS 1e-8f
#define LOG2E 1.44269504088896340736f
#define SCALE1 0x7F7F7F7Fu   // E8M0 = 127 -> 2^0 in every byte

typedef __attribute__((ext_vector_type(8))) int int8v;
typedef __attribute__((ext_vector_type(16))) float f32x16;

union FragU { int4 q[2]; int8v v; };

// ---------------------------------------------------------------------------
// fp8 frag-linear layout (per matrix, 8 MB):
//   chunk = grp32*8 + k64 (grp32 0..511, k64 0..7), 2048 B = two 1024 B halves.
//   lane l, elem j: byte = chunk*2048 + h*1024 + l*16 + j
//   row = grp32*32 + (l&31), k = k64*64 + (l>>5)*32 + h*16 + j
//   A and B share this (lane,elem)->k bijection => dot correct regardless of
//   HW k-order; uniform MX scales (2^0) make block mapping irrelevant.
// ws layout (bytes):
//   [0,        8388608)   imgF fp8
//   [8388608,  16777216)  txtF fp8
//   [16777216, 33554432)  colpart float [64 rb][4 wave][16384]
//   [33554432, 34078720)  rowpart float [8 split][16384]
//   [34078720, 34144256)  colLSE float [16384]
//   [34144256, 34209792)  diag   float [16384]
// ---------------------------------------------------------------------------

__global__ __launch_bounds__(256) void convert_kernel(
    const float* __restrict__ img, const float* __restrict__ txt,
    const float* __restrict__ scale_p,
    char* __restrict__ imgF, char* __restrict__ txtF) {
  const float fac = sqrtf((*scale_p) * LOG2E);  // exp(scale*S) = exp2(dot of scaled inputs)
  const float* src = blockIdx.y ? txt : img;
  char* dst = blockIdx.y ? txtF : imgF;
  int tm = blockIdx.x * 256 + threadIdx.x;      // 0..524287
  int c = tm >> 7;                               // chunk 0..4095
  int h = (tm >> 6) & 1;
  int l = tm & 63;
  int grp32 = c >> 3, k64 = c & 7;
  int row = grp32 * 32 + (l & 31);
  int kb = k64 * 64 + ((l >> 5) << 5) + h * 16;
  const float* p = src + (size_t)row * DIM + kb;
  float f[16];
#pragma unroll
  for (int e = 0; e < 16; ++e) f[e] = p[e] * fac;
  int4 w;
  int w0 = 0, w1 = 0, w2 = 0, w3 = 0;
  w0 = __builtin_amdgcn_cvt_pk_fp8_f32(f[0],  f[1],  w0, false);
  w0 = __builtin_amdgcn_cvt_pk_fp8_f32(f[2],  f[3],  w0, true);
  w1 = __builtin_amdgcn_cvt_pk_fp8_f32(f[4],  f[5],  w1, false);
  w1 = __builtin_amdgcn_cvt_pk_fp8_f32(f[6],  f[7],  w1, true);
  w2 = __builtin_amdgcn_cvt_pk_fp8_f32(f[8],  f[9],  w2, false);
  w2 = __builtin_amdgcn_cvt_pk_fp8_f32(f[10], f[11], w2, true);
  w3 = __builtin_amdgcn_cvt_pk_fp8_f32(f[12], f[13], w3, false);
  w3 = __builtin_amdgcn_cvt_pk_fp8_f32(f[14], f[15], w3, true);
  w.x = w0; w.y = w1; w.z = w2; w.w = w3;
  *reinterpret_cast<int4*>(dst + (size_t)c * 2048 + h * 1024 + l * 16) = w;
}

// ---------------------------------------------------------------------------
// Fused fp8 GEMM + row/col sum-exp. 4 waves/block, 2 blocks/CU (independent
// barriers -> tail of one block overlaps MFMAs of the other). Wave owns 64
// rows (A in regs/AGPRs, Rm=2). Panel = 32 cols x 512 K fp8 (16 KB), dbuf.
// Per-wave col-partials go straight to global (no cross-wave LDS merge).
// grid = (split 8, rb 64) = 512 blocks.
// ---------------------------------------------------------------------------
__global__ __launch_bounds__(256, 2) void fused_lse_kernel(
    const char* __restrict__ imgF, const char* __restrict__ txtF,
    float* __restrict__ rowpart,   // [8][16384]
    float* __restrict__ colpart) { // [64][4][16384]
  const int split = blockIdx.x;          // 0..7 : 2048-col slice
  const int rb    = blockIdx.y;          // 0..63: 256-row block
  const int wid = threadIdx.x >> 6;      // 0..3
  const int l   = threadIdx.x & 63;

  __shared__ int4 BsV[2][1024];          // 2 x 16KB B panel
  char* Bsb = reinterpret_cast<char*>(&BsV[0][0]);

  // prologue: stage panel ct=0 into buf 0 (wave stages 4 x 1KB)
  {
    const char* pb = txtF + (size_t)(split * 64) * 16384;
#pragma unroll
    for (int j = 0; j < 4; ++j) {
      int off = (4 * wid + j) * 1024;
      __builtin_amdgcn_global_load_lds(
          (const __attribute__((address_space(1))) unsigned int*)(pb + off + l * 16),
          (__attribute__((address_space(3))) unsigned int*)(Bsb + off), 16, 0, 0);
    }
  }

  // A: 64 rows x 512 K fp8 in registers (2 rg x 8 k64 x 8 regs = 128)
  const int grp0 = rb * 8 + wid * 2;
  int8v afrag[2][8];
#pragma unroll
  for (int rg = 0; rg < 2; ++rg)
#pragma unroll
    for (int k = 0; k < 8; ++k) {
      const char* ap = imgF + ((size_t)(grp0 + rg) * 8 + k) * 2048 + l * 16;
      FragU u;
      u.q[0] = *reinterpret_cast<const int4*>(ap);
      u.q[1] = *reinterpret_cast<const int4*>(ap + 1024);
      afrag[rg][k] = u.v;
    }
  asm volatile("" ::: "memory");
  __syncthreads();

  float rowsum0[16], rowsum1[16];
#pragma unroll
  for (int r = 0; r < 16; ++r) { rowsum0[r] = 0.f; rowsum1[r] = 0.f; }

  const int NCT = 64;                    // 32-col panels per block
  for (int ct = 0; ct < NCT; ++ct) {
    const int cur = ct & 1;
    if (ct + 1 < NCT) {                  // stage next panel; latency hidden under MFMAs
      const char* pb = txtF + (size_t)(split * 64 + ct + 1) * 16384;
      char* db = Bsb + (cur ^ 1) * 16384;
#pragma unroll
      for (int j = 0; j < 4; ++j) {
        int off = (4 * wid + j) * 1024;
        __builtin_amdgcn_global_load_lds(
            (const __attribute__((address_space(1))) unsigned int*)(pb + off + l * 16),
            (__attribute__((address_space(3))) unsigned int*)(db + off), 16, 0, 0);
      }
    }
    f32x16 acc0, acc1;
#pragma unroll
    for (int r = 0; r < 16; ++r) { acc0[r] = 0.f; acc1[r] = 0.f; }
    __builtin_amdgcn_s_setprio(1);
#pragma unroll
    for (int k = 0; k < 8; ++k) {        // one B-frag -> 2 MFMAs (Rm=2)
      const char* bp = Bsb + cur * 16384 + k * 2048 + l * 16;
      FragU b;
      b.q[0] = *reinterpret_cast<const int4*>(bp);
      b.q[1] = *reinterpret_cast<const int4*>(bp + 1024);
      acc0 = __builtin_amdgcn_mfma_scale_f32_32x32x64_f8f6f4(
          afrag[0][k], b.v, acc0, 0, 0, 0, SCALE1, 0, SCALE1);
      acc1 = __builtin_amdgcn_mfma_scale_f32_32x32x64_f8f6f4(
          afrag[1][k], b.v, acc1, 0, 0, 0, SCALE1, 0, SCALE1);
    }
    __builtin_amdgcn_s_setprio(0);
    // tail: exp feeds row- and col-sums; no max needed (|arg| < ~2.2)
    float colp = 0.f;
#pragma unroll
    for (int r = 0; r < 16; ++r) {
      float e0 = exp2f(acc0[r]);
      float e1 = exp2f(acc1[r]);
      rowsum0[r] += e0; rowsum1[r] += e1;
      colp += e0 + e1;
    }
    colp += __shfl_xor(colp, 32, 64);    // merge row-halves per col
    if (l < 32)                          // per-wave col partial -> global (coalesced)
      colpart[((size_t)(rb * 4 + wid)) * N_TOT + (size_t)(split * 64 + ct) * 32 + l] = colp;
    __syncthreads();                     // B-buffer WAR protection (drains stage vmcnt)
  }

  // row sums: butterfly over 32 col-lanes (deterministic)
#pragma unroll
  for (int r = 0; r < 16; ++r) {
    float s0 = rowsum0[r], s1 = rowsum1[r];
#pragma unroll
    for (int off = 1; off < 32; off <<= 1) {
      s0 += __shfl_xor(s0, off, 64);
      s1 += __shfl_xor(s1, off, 64);
    }
    rowsum0[r] = s0; rowsum1[r] = s1;
  }
  if ((l & 31) == 0) {
    int rbase = rb * 256 + wid * 64 + ((l >> 5) << 2);
#pragma unroll
    for (int r = 0; r < 16; ++r) {
      int rr = (r & 3) + ((r >> 2) << 3);
      rowpart[(size_t)split * N_TOT + rbase + rr] = rowsum0[r];
      rowpart[(size_t)split * N_TOT + rbase + 32 + rr] = rowsum1[r];
    }
  }
}

// exact fp32 diagonal: one wave per row
__global__ __launch_bounds__(256) void diag_kernel(
    const float* __restrict__ img, const float* __restrict__ txt,
    float* __restrict__ diag) {
  int wid = threadIdx.x >> 6, l = threadIdx.x & 63;
  int row = blockIdx.x * 4 + wid;
  const float4* a = reinterpret_cast<const float4*>(img + (size_t)row * DIM) + l * 2;
  const float4* b = reinterpret_cast<const float4*>(txt + (size_t)row * DIM) + l * 2;
  float s = 0.f;
#pragma unroll
  for (int j = 0; j < 2; ++j) {
    float4 x = a[j], y = b[j];
    s += x.x * y.x + x.y * y.y + x.z * y.z + x.w * y.w;
  }
#pragma unroll
  for (int off = 32; off > 0; off >>= 1) s += __shfl_down(s, off, 64);
  if (l == 0) diag[row] = s;
}

// per-column: sum 256 partials, take log
__global__ __launch_bounds__(256) void colreduce_kernel(
    const float* __restrict__ colpart, float* __restrict__ colLSE) {
  int col = blockIdx.x * 256 + threadIdx.x;
  float s = 0.f;
#pragma unroll 8
  for (int g = 0; g < 256; ++g) s += colpart[(size_t)g * N_TOT + col];
  colLSE[col] = __logf(s + EPS);
}

// merge row partials, add col LSEs and diagonal, single-block reduce
__global__ __launch_bounds__(256) void final_kernel(
    const float* __restrict__ rowpart, const float* __restrict__ colLSE,
    const float* __restrict__ diag, const float* __restrict__ scale_p,
    float* __restrict__ out) {
  int t = threadIdx.x;
  float sden = 0.f, sdiag = 0.f;
  for (int i = t; i < N_TOT; i += 256) {
    float rs = 0.f;
#pragma unroll
    for (int sp = 0; sp < 8; ++sp) rs += rowpart[(size_t)sp * N_TOT + i];
    sden += __logf(rs + EPS) + colLSE[i];
    sdiag += diag[i];
  }
  __shared__ float rA[256], rB[256];
  rA[t] = sden; rB[t] = sdiag;
  __syncthreads();
  for (int s2 = 128; s2 > 0; s2 >>= 1) {
    if (t < s2) { rA[t] += rA[t + s2]; rB[t] += rB[t + s2]; }
    __syncthreads();
  }
  if (t == 0)
    out[0] = 0.5f * rA[0] / (float)N_TOT - (*scale_p) * rB[0] / (float)N_TOT;
}

extern "C" void kernel_launch(void* const* d_in, const int* in_sizes, int n_in,
                              void* d_out, int out_size, void* d_ws, size_t ws_size,
                              hipStream_t stream) {
  const float* img     = (const float*)d_in[0];
  const float* txt     = (const float*)d_in[1];
  const float* scale_p = (const float*)d_in[2];
  float* out = (float*)d_out;
  char* ws = (char*)d_ws;   // needs ~34.2 MB
  char*  imgF    = ws;
  char*  txtF    = ws + (size_t)8388608;
  float* colpart = (float*)(ws + (size_t)16777216);
  float* rowpart = (float*)(ws + (size_t)33554432);
  float* colLSE  = (float*)(ws + (size_t)34078720);
  float* diag    = (float*)(ws + (size_t)34144256);

  convert_kernel<<<dim3(2048, 2, 1), 256, 0, stream>>>(img, txt, scale_p, imgF, txtF);
  fused_lse_kernel<<<dim3(8, 64, 1), 256, 0, stream>>>(imgF, txtF, rowpart, colpart);
  diag_kernel<<<dim3(4096, 1, 1), 256, 0, stream>>>(img, txt, diag);
  colreduce_kernel<<<dim3(64, 1, 1), 256, 0, stream>>>(colpart, colLSE);
  final_kernel<<<dim3(1, 1, 1), 256, 0, stream>>>(rowpart, colLSE, diag, scale_p, out);
}

// Round 8
// 230.278 us; speedup vs baseline: 1.0258x; 1.0258x over previous
//
#include <hip/hip_runtime.h>
#include <cstdint>
#include <cstddef>

#define N_TOT 16384
#define DIM 512
#define EPS 1e-8f
#define LOG2E 1.44269504088896340736f
#define SCALE1 0x7F7F7F7Fu   // E8M0 = 127 -> 2^0 in every byte

typedef __attribute__((ext_vector_type(8))) int int8v;
typedef __attribute__((ext_vector_type(16))) float f32x16;

union FragU { int4 q[2]; int8v v; };

// ---------------------------------------------------------------------------
// fp8 frag-linear layout (per matrix, 8 MB):
//   chunk = grp32*8 + k64 (grp32 0..511, k64 0..7), 2048 B = two 1024 B halves.
//   lane l, elem j: byte = chunk*2048 + h*1024 + l*16 + j
//   row = grp32*32 + (l&31), k = k64*64 + (l>>5)*32 + h*16 + j
//   A and B share this (lane,elem)->k bijection => dot correct regardless of
//   HW k-order; uniform MX scales (2^0) make block mapping irrelevant.
// ws layout (bytes):
//   [0,        8388608)   imgF fp8
//   [8388608,  16777216)  txtF fp8
//   [16777216, 33554432)  colpart float [64 rb][4 wave][16384]
//   [33554432, 34078720)  rowpart float [8 split][16384]
//   [34078720, 34144256)  colLSE float [16384]
//   [34144256, 34209792)  diag   float [16384]
// ---------------------------------------------------------------------------

__global__ __launch_bounds__(256) void convert_kernel(
    const float* __restrict__ img, const float* __restrict__ txt,
    const float* __restrict__ scale_p,
    char* __restrict__ imgF, char* __restrict__ txtF) {
  const float fac = sqrtf((*scale_p) * LOG2E);  // exp(scale*S) = exp2(dot of scaled inputs)
  const float* src = blockIdx.y ? txt : img;
  char* dst = blockIdx.y ? txtF : imgF;
  int tm = blockIdx.x * 256 + threadIdx.x;      // 0..524287
  int c = tm >> 7;                               // chunk 0..4095
  int h = (tm >> 6) & 1;
  int l = tm & 63;
  int grp32 = c >> 3, k64 = c & 7;
  int row = grp32 * 32 + (l & 31);
  int kb = k64 * 64 + ((l >> 5) << 5) + h * 16;
  const float* p = src + (size_t)row * DIM + kb;
  float f[16];
#pragma unroll
  for (int e = 0; e < 16; ++e) f[e] = p[e] * fac;
  int4 w;
  int w0 = 0, w1 = 0, w2 = 0, w3 = 0;
  w0 = __builtin_amdgcn_cvt_pk_fp8_f32(f[0],  f[1],  w0, false);
  w0 = __builtin_amdgcn_cvt_pk_fp8_f32(f[2],  f[3],  w0, true);
  w1 = __builtin_amdgcn_cvt_pk_fp8_f32(f[4],  f[5],  w1, false);
  w1 = __builtin_amdgcn_cvt_pk_fp8_f32(f[6],  f[7],  w1, true);
  w2 = __builtin_amdgcn_cvt_pk_fp8_f32(f[8],  f[9],  w2, false);
  w2 = __builtin_amdgcn_cvt_pk_fp8_f32(f[10], f[11], w2, true);
  w3 = __builtin_amdgcn_cvt_pk_fp8_f32(f[12], f[13], w3, false);
  w3 = __builtin_amdgcn_cvt_pk_fp8_f32(f[14], f[15], w3, true);
  w.x = w0; w.y = w1; w.z = w2; w.w = w3;
  *reinterpret_cast<int4*>(dst + (size_t)c * 2048 + h * 1024 + l * 16) = w;
}

// ---------------------------------------------------------------------------
// Fused fp8 GEMM + row/col sum-exp. 4 waves/block, 2 blocks/CU. Wave owns 64
// rows; A is PINNED in VGPRs as 128 SCALAR ints via tied inline-asm (scalar
// "+v" is supported; aggregate "+v" is not). Compiler cannot re-sink the A
// loads into the K-loop -> no per-panel A refetch. Panel = 32 cols x 512 K
// fp8 (16 KB), dbuf LDS. grid = (split 8, rb 64) = 512 blocks.
// ---------------------------------------------------------------------------
__global__ __launch_bounds__(256, 2) void fused_lse_kernel(
    const char* __restrict__ imgF, const char* __restrict__ txtF,
    float* __restrict__ rowpart,   // [8][16384]
    float* __restrict__ colpart) { // [64][4][16384]
  const int split = blockIdx.x;          // 0..7 : 2048-col slice
  const int rb    = blockIdx.y;          // 0..63: 256-row block
  const int wid = threadIdx.x >> 6;      // 0..3
  const int l   = threadIdx.x & 63;

  __shared__ int4 BsV[2][1024];          // 2 x 16KB B panel
  char* Bsb = reinterpret_cast<char*>(&BsV[0][0]);

  // prologue: stage panel ct=0 into buf 0 (wave stages 4 x 1KB)
  {
    const char* pb = txtF + (size_t)(split * 64) * 16384;
#pragma unroll
    for (int j = 0; j < 4; ++j) {
      int off = (4 * wid + j) * 1024;
      __builtin_amdgcn_global_load_lds(
          (const __attribute__((address_space(1))) unsigned int*)(pb + off + l * 16),
          (__attribute__((address_space(3))) unsigned int*)(Bsb + off), 16, 0, 0);
    }
  }

  // A: 64 rows x 512 K fp8 as 128 scalar ints (2 rg x 8 k64 x 8 dwords)
  const int grp0 = rb * 8 + wid * 2;
  int av[2][8][8];
#pragma unroll
  for (int rg = 0; rg < 2; ++rg)
#pragma unroll
    for (int k = 0; k < 8; ++k) {
      const char* ap = imgF + ((size_t)(grp0 + rg) * 8 + k) * 2048 + l * 16;
      int4 q0 = *reinterpret_cast<const int4*>(ap);
      int4 q1 = *reinterpret_cast<const int4*>(ap + 1024);
      av[rg][k][0] = q0.x; av[rg][k][1] = q0.y; av[rg][k][2] = q0.z; av[rg][k][3] = q0.w;
      av[rg][k][4] = q1.x; av[rg][k][5] = q1.y; av[rg][k][6] = q1.z; av[rg][k][7] = q1.w;
    }
  // Opaque pin (scalar tied operands): values become asm-defined -> cannot be
  // rematerialized by reloading from global inside the loop.
#pragma unroll
  for (int rg = 0; rg < 2; ++rg)
#pragma unroll
    for (int k = 0; k < 8; ++k) {
      asm volatile("" : "+v"(av[rg][k][0]), "+v"(av[rg][k][1]),
                        "+v"(av[rg][k][2]), "+v"(av[rg][k][3]),
                        "+v"(av[rg][k][4]), "+v"(av[rg][k][5]),
                        "+v"(av[rg][k][6]), "+v"(av[rg][k][7]));
    }
  __syncthreads();

  float rowsum0[16], rowsum1[16];
#pragma unroll
  for (int r = 0; r < 16; ++r) { rowsum0[r] = 0.f; rowsum1[r] = 0.f; }

  const int NCT = 64;                    // 32-col panels per block
  for (int ct = 0; ct < NCT; ++ct) {
    const int cur = ct & 1;
    if (ct + 1 < NCT) {                  // stage next panel; latency hidden under MFMAs
      const char* pb = txtF + (size_t)(split * 64 + ct + 1) * 16384;
      char* db = Bsb + (cur ^ 1) * 16384;
#pragma unroll
      for (int j = 0; j < 4; ++j) {
        int off = (4 * wid + j) * 1024;
        __builtin_amdgcn_global_load_lds(
            (const __attribute__((address_space(1))) unsigned int*)(pb + off + l * 16),
            (__attribute__((address_space(3))) unsigned int*)(db + off), 16, 0, 0);
      }
    }
    f32x16 acc0, acc1;
#pragma unroll
    for (int r = 0; r < 16; ++r) { acc0[r] = 0.f; acc1[r] = 0.f; }
    __builtin_amdgcn_s_setprio(1);
#pragma unroll
    for (int k = 0; k < 8; ++k) {        // one B-frag -> 2 MFMAs (Rm=2)
      const char* bp = Bsb + cur * 16384 + k * 2048 + l * 16;
      FragU b;
      b.q[0] = *reinterpret_cast<const int4*>(bp);
      b.q[1] = *reinterpret_cast<const int4*>(bp + 1024);
      int8v a0v, a1v;
#pragma unroll
      for (int e = 0; e < 8; ++e) { a0v[e] = av[0][k][e]; a1v[e] = av[1][k][e]; }
      acc0 = __builtin_amdgcn_mfma_scale_f32_32x32x64_f8f6f4(
          a0v, b.v, acc0, 0, 0, 0, SCALE1, 0, SCALE1);
      acc1 = __builtin_amdgcn_mfma_scale_f32_32x32x64_f8f6f4(
          a1v, b.v, acc1, 0, 0, 0, SCALE1, 0, SCALE1);
    }
    __builtin_amdgcn_s_setprio(0);
    // tail: exp feeds row- and col-sums; no max needed (|arg| < ~2.2)
    float colp = 0.f;
#pragma unroll
    for (int r = 0; r < 16; ++r) {
      float e0 = exp2f(acc0[r]);
      float e1 = exp2f(acc1[r]);
      rowsum0[r] += e0; rowsum1[r] += e1;
      colp += e0 + e1;
    }
    colp += __shfl_xor(colp, 32, 64);    // merge row-halves per col
    if (l < 32)                          // per-wave col partial -> global (coalesced)
      colpart[((size_t)(rb * 4 + wid)) * N_TOT + (size_t)(split * 64 + ct) * 32 + l] = colp;
    __syncthreads();                     // B-buffer WAR protection (drains stage vmcnt)
  }

  // row sums: butterfly over 32 col-lanes (deterministic)
#pragma unroll
  for (int r = 0; r < 16; ++r) {
    float s0 = rowsum0[r], s1 = rowsum1[r];
#pragma unroll
    for (int off = 1; off < 32; off <<= 1) {
      s0 += __shfl_xor(s0, off, 64);
      s1 += __shfl_xor(s1, off, 64);
    }
    rowsum0[r] = s0; rowsum1[r] = s1;
  }
  if ((l & 31) == 0) {
    int rbase = rb * 256 + wid * 64 + ((l >> 5) << 2);
#pragma unroll
    for (int r = 0; r < 16; ++r) {
      int rr = (r & 3) + ((r >> 2) << 3);
      rowpart[(size_t)split * N_TOT + rbase + rr] = rowsum0[r];
      rowpart[(size_t)split * N_TOT + rbase + 32 + rr] = rowsum1[r];
    }
  }
}

// exact fp32 diagonal: one wave per row
__global__ __launch_bounds__(256) void diag_kernel(
    const float* __restrict__ img, const float* __restrict__ txt,
    float* __restrict__ diag) {
  int wid = threadIdx.x >> 6, l = threadIdx.x & 63;
  int row = blockIdx.x * 4 + wid;
  const float4* a = reinterpret_cast<const float4*>(img + (size_t)row * DIM) + l * 2;
  const float4* b = reinterpret_cast<const float4*>(txt + (size_t)row * DIM) + l * 2;
  float s = 0.f;
#pragma unroll
  for (int j = 0; j < 2; ++j) {
    float4 x = a[j], y = b[j];
    s += x.x * y.x + x.y * y.y + x.z * y.z + x.w * y.w;
  }
#pragma unroll
  for (int off = 32; off > 0; off >>= 1) s += __shfl_down(s, off, 64);
  if (l == 0) diag[row] = s;
}

// per-column: sum 256 partials, take log
__global__ __launch_bounds__(256) void colreduce_kernel(
    const float* __restrict__ colpart, float* __restrict__ colLSE) {
  int col = blockIdx.x * 256 + threadIdx.x;
  float s = 0.f;
#pragma unroll 8
  for (int g = 0; g < 256; ++g) s += colpart[(size_t)g * N_TOT + col];
  colLSE[col] = __logf(s + EPS);
}

// merge row partials, add col LSEs and diagonal, single-block reduce
__global__ __launch_bounds__(256) void final_kernel(
    const float* __restrict__ rowpart, const float* __restrict__ colLSE,
    const float* __restrict__ diag, const float* __restrict__ scale_p,
    float* __restrict__ out) {
  int t = threadIdx.x;
  float sden = 0.f, sdiag = 0.f;
  for (int i = t; i < N_TOT; i += 256) {
    float rs = 0.f;
#pragma unroll
    for (int sp = 0; sp < 8; ++sp) rs += rowpart[(size_t)sp * N_TOT + i];
    sden += __logf(rs + EPS) + colLSE[i];
    sdiag += diag[i];
  }
  __shared__ float rA[256], rB[256];
  rA[t] = sden; rB[t] = sdiag;
  __syncthreads();
  for (int s2 = 128; s2 > 0; s2 >>= 1) {
    if (t < s2) { rA[t] += rA[t + s2]; rB[t] += rB[t + s2]; }
    __syncthreads();
  }
  if (t == 0)
    out[0] = 0.5f * rA[0] / (float)N_TOT - (*scale_p) * rB[0] / (float)N_TOT;
}

extern "C" void kernel_launch(void* const* d_in, const int* in_sizes, int n_in,
                              void* d_out, int out_size, void* d_ws, size_t ws_size,
                              hipStream_t stream) {
  const float* img     = (const float*)d_in[0];
  const float* txt     = (const float*)d_in[1];
  const float* scale_p = (const float*)d_in[2];
  float* out = (float*)d_out;
  char* ws = (char*)d_ws;   // needs ~34.2 MB
  char*  imgF    = ws;
  char*  txtF    = ws + (size_t)8388608;
  float* colpart = (float*)(ws + (size_t)16777216);
  float* rowpart = (float*)(ws + (size_t)33554432);
  float* colLSE  = (float*)(ws + (size_t)34078720);
  float* diag    = (float*)(ws + (size_t)34144256);

  convert_kernel<<<dim3(2048, 2, 1), 256, 0, stream>>>(img, txt, scale_p, imgF, txtF);
  fused_lse_kernel<<<dim3(8, 64, 1), 256, 0, stream>>>(imgF, txtF, rowpart, colpart);
  diag_kernel<<<dim3(4096, 1, 1), 256, 0, stream>>>(img, txt, diag);
  colreduce_kernel<<<dim3(64, 1, 1), 256, 0, stream>>>(colpart, colLSE);
  final_kernel<<<dim3(1, 1, 1), 256, 0, stream>>>(rowpart, colLSE, diag, scale_p, out);
}